// Round 4
// baseline (541.920 us; speedup 1.0000x reference)
//
#include <hip/hip_runtime.h>
#include <cstdint>
#include <cstddef>

// Problem constants
#define NTOK 2048      // B*S
#define DDIM 1024
#define FDIM 2048
#define NEXP 14
#define MAXT 2048

typedef __attribute__((ext_vector_type(8))) short short8;
typedef __attribute__((ext_vector_type(4))) float floatx4;

__device__ __forceinline__ unsigned pack2bf(float lo, float hi) {
    unsigned a = __float_as_uint(lo), b = __float_as_uint(hi);
    return ((a + 0x8000u) >> 16) | ((b + 0x8000u) & 0xffff0000u);
}
__device__ __forceinline__ unsigned short f2bf1(float f) {
    return (unsigned short)((__float_as_uint(f) + 0x8000u) >> 16);
}

// async global->LDS, 16B per lane; lds base must be wave-uniform (HW adds lane*16)
__device__ __forceinline__ void glds16(const void* g, void* lds) {
    __builtin_amdgcn_global_load_lds((const __attribute__((address_space(1))) unsigned*)g,
                                     (__attribute__((address_space(3))) unsigned*)lds, 16, 0, 0);
}

// ---------------- convert x -> bf16, zero counters ----------------
__global__ __launch_bounds__(256) void cvtx_kernel(const float* __restrict__ x,
                                                   unsigned short* __restrict__ xb,
                                                   int* __restrict__ cnt) {
    if (blockIdx.x == 0 && threadIdx.x < NEXP) cnt[threadIdx.x] = 0;
    const size_t i = ((size_t)blockIdx.x * 256 + threadIdx.x) * 8;
    float4 a = *(const float4*)(x + i);
    float4 b = *(const float4*)(x + i + 4);
    uint4 u;
    u.x = pack2bf(a.x, a.y); u.y = pack2bf(a.z, a.w);
    u.z = pack2bf(b.x, b.y); u.w = pack2bf(b.z, b.w);
    *(uint4*)(xb + i) = u;
}

// ---------------- weight transpose+convert: src[K][N] fp32 -> dst[N][K] bf16 ----------------
// block = 256 thr handles 64 n x 128 k; lane-coalesced strided reads, 64B/lane writes
__global__ __launch_bounds__(256) void cvtw_kernel(
    const float* __restrict__ src, unsigned short* __restrict__ dst,
    int K, int N, int kt, int tpe)
{
    const int b = blockIdx.x;
    const int e = b / tpe, r = b % tpe;
    const int n = (r / kt) * 64 + (threadIdx.x & 63);
    const int kq = (r % kt) * 128 + (threadIdx.x >> 6) * 32;
    const float* s = src + (size_t)e * K * N + (size_t)kq * N + n;
    float v[32];
#pragma unroll
    for (int j = 0; j < 32; ++j) v[j] = s[(size_t)j * N];
    unsigned us[16];
#pragma unroll
    for (int q = 0; q < 16; ++q) us[q] = pack2bf(v[2 * q], v[2 * q + 1]);
    unsigned short* d = dst + (size_t)e * K * N + (size_t)n * K + kq;
    *(uint4*)(d)      = uint4{us[0],  us[1],  us[2],  us[3]};
    *(uint4*)(d + 8)  = uint4{us[4],  us[5],  us[6],  us[7]};
    *(uint4*)(d + 16) = uint4{us[8],  us[9],  us[10], us[11]};
    *(uint4*)(d + 24) = uint4{us[12], us[13], us[14], us[15]};
}

// ---------------- gating: one wave per token ----------------
__global__ __launch_bounds__(256) void gate_kernel(
    const float* __restrict__ x, const float* __restrict__ gw,
    int* __restrict__ cnt, int* __restrict__ lists, float* __restrict__ wt)
{
    const int wave = threadIdx.x >> 6, lane = threadIdx.x & 63;
    const int n = blockIdx.x * 4 + wave;
    float part[NEXP];
#pragma unroll
    for (int e = 0; e < NEXP; ++e) part[e] = 0.f;
    const float4* xr = (const float4*)(x + (size_t)n * DDIM);
#pragma unroll
    for (int kk = 0; kk < 4; ++kk) {
        const float4 xv = xr[kk * 64 + lane];
#pragma unroll
        for (int e = 0; e < NEXP; ++e) {
            const float4 g = ((const float4*)(gw + e * DDIM))[kk * 64 + lane];
            part[e] = fmaf(xv.x, g.x, fmaf(xv.y, g.y, fmaf(xv.z, g.z, fmaf(xv.w, g.w, part[e]))));
        }
    }
#pragma unroll
    for (int e = 0; e < NEXP; ++e) {
        float v = part[e];
        for (int off = 32; off; off >>= 1) v += __shfl_xor(v, off);
        part[e] = v;
    }
    int i0 = 0; float l0 = part[0];
#pragma unroll
    for (int e = 1; e < NEXP; ++e) if (part[e] > l0) { l0 = part[e]; i0 = e; }
    int i1 = -1; float l1 = -3.0e38f;
#pragma unroll
    for (int e = 0; e < NEXP; ++e) if (e != i0 && part[e] > l1) { l1 = part[e]; i1 = e; }
    if (lane == 0) {
        const float r  = __expf(l1 - l0);
        wt[2 * n]     = 1.f / (1.f + r);
        wt[2 * n + 1] = r / (1.f + r);
        int p0 = atomicAdd(&cnt[i0], 1); lists[i0 * MAXT + p0] = 2 * n;
        int p1 = atomicAdd(&cnt[i1], 1); lists[i1 * MAXT + p1] = 2 * n + 1;
    }
}

// ---------------- build compact (expert, m-tile) job list ----------------
#define MAXJOBS 78
__global__ void jobs_kernel(const int* __restrict__ cnt, int* __restrict__ job_e,
                            int* __restrict__ job_mt, int* __restrict__ njobs) {
    if (threadIdx.x == 0) {
        int J = 0;
        for (int e = 0; e < NEXP; ++e) {
            const int m = (cnt[e] + 63) >> 6;
            for (int i = 0; i < m; ++i) { job_e[J] = e; job_mt[J] = i; ++J; }
        }
        njobs[0] = J;
    }
}

// ---------------- GEMM1: hh[p][F] = gelu(xb[tok] @ w1t[e]^T + b1[e]) ----------------
// BM=64, BN=128, BK=32; all staging via glds16, granule-linear LDS (conflict-free).
__global__ __launch_bounds__(256) void gemm1_kernel(
    const unsigned short* __restrict__ xb, const unsigned short* __restrict__ w1t,
    const float* __restrict__ b1, const int* __restrict__ cnt,
    const int* __restrict__ lists, const int* __restrict__ job_e,
    const int* __restrict__ job_mt, const int* __restrict__ njobs,
    unsigned short* __restrict__ hh)
{
    const int j = blockIdx.y;
    if (j >= njobs[0]) return;
    const int e = job_e[j], mt = job_mt[j], nt = blockIdx.x;
    const int count = cnt[e];
    const int* list = lists + e * MAXT + mt * 64;
    const int mloc = min(64, count - mt * 64);

    __shared__ __align__(16) unsigned short As[2][64 * 32];    // 4 KB / buf
    __shared__ __align__(16) unsigned short Bs[2][128 * 32];   // 8 KB / buf

    const int t = threadIdx.x, lane = t & 63, w = t >> 6;
    const int lrow = lane & 15, lq = lane >> 4;

    // A gather: wave w stages m-block w; lane -> (m = w*16+lrow, kc = lq)
    const int arow = w * 16 + lrow;
    const int atok = list[min(arow, mloc - 1)] >> 1;
    const unsigned short* aG = xb + (size_t)atok * DDIM + lq * 8;
    // B: wave w stages n-blocks w and w+4; lane -> (n = blk*16+lrow, kc = lq)
    const int nA = nt * 128 + w * 16 + lrow;
    const unsigned short* bG0 = w1t + ((size_t)e * FDIM + nA) * DDIM + lq * 8;
    const unsigned short* bG1 = bG0 + (size_t)64 * DDIM;

    floatx4 acc[4][2];
#pragma unroll
    for (int i = 0; i < 4; ++i)
#pragma unroll
        for (int jn = 0; jn < 2; ++jn) acc[i][jn] = (floatx4)0.f;

    glds16(aG, &As[0][w * 512]);
    glds16(bG0, &Bs[0][w * 512]);
    glds16(bG1, &Bs[0][(w + 4) * 512]);

    int p = 0;
    for (int k0 = 0; k0 < DDIM; k0 += 32) {
        __syncthreads();
        if (k0 + 32 < DDIM) {
            glds16(aG + k0 + 32, &As[p ^ 1][w * 512]);
            glds16(bG0 + k0 + 32, &Bs[p ^ 1][w * 512]);
            glds16(bG1 + k0 + 32, &Bs[p ^ 1][(w + 4) * 512]);
        }
        short8 af[4], bf[2];
#pragma unroll
        for (int i = 0; i < 4; ++i)
            af[i] = *(const short8*)&As[p][i * 512 + lane * 8];
#pragma unroll
        for (int jn = 0; jn < 2; ++jn)
            bf[jn] = *(const short8*)&Bs[p][(2 * w + jn) * 512 + lane * 8];
#pragma unroll
        for (int i = 0; i < 4; ++i)
#pragma unroll
            for (int jn = 0; jn < 2; ++jn)
                acc[i][jn] = __builtin_amdgcn_mfma_f32_16x16x32_bf16(af[i], bf[jn], acc[i][jn], 0, 0, 0);
        p ^= 1;
    }
    // epilogue: bias + exact gelu -> hh (bf16)
#pragma unroll
    for (int jn = 0; jn < 2; ++jn) {
        const int n = nt * 128 + w * 32 + jn * 16 + lrow;
        const float bias = b1[e * FDIM + n];
#pragma unroll
        for (int i = 0; i < 4; ++i) {
#pragma unroll
            for (int r = 0; r < 4; ++r) {
                const int m = i * 16 + lq * 4 + r;
                if (m < mloc) {
                    const int pp = list[m];
                    float v = acc[i][jn][r] + bias;
                    v = 0.5f * v * (1.0f + erff(v * 0.70710678118654752f));
                    hh[(size_t)pp * FDIM + n] = f2bf1(v);
                }
            }
        }
    }
}

// ---------------- GEMM2: out_slot[tok][D] = wt[p] * (hh[p] @ w2t[e]^T + b2[e]) ----------------
// BM=64, BN=64, BK=64; pure glds16 staging, direct stores.
__global__ __launch_bounds__(256) void gemm2_kernel(
    const unsigned short* __restrict__ hh, const unsigned short* __restrict__ w2t,
    const float* __restrict__ b2, const int* __restrict__ cnt,
    const int* __restrict__ lists, const int* __restrict__ job_e,
    const int* __restrict__ job_mt, const int* __restrict__ njobs,
    const float* __restrict__ wt, float* __restrict__ out0, float* __restrict__ out1)
{
    const int j = blockIdx.y;
    if (j >= njobs[0]) return;
    const int e = job_e[j], mt = job_mt[j], nt = blockIdx.x;
    const int count = cnt[e];
    const int* list = lists + e * MAXT + mt * 64;
    const int mloc = min(64, count - mt * 64);

    __shared__ __align__(16) unsigned short As[2][64 * 64];   // 8 KB / buf
    __shared__ __align__(16) unsigned short Bs[2][64 * 64];   // 8 KB / buf

    const int t = threadIdx.x, lane = t & 63, w = t >> 6;
    const int lrow = lane & 15, lq = lane >> 4;
    const int wm = (w & 1) * 32, wn = (w >> 1) * 32;

    const int arow = w * 16 + lrow;
    const int apair = list[min(arow, mloc - 1)];
    const unsigned short* aG = hh + (size_t)apair * FDIM + lq * 8;
    const int nB = nt * 64 + w * 16 + lrow;
    const unsigned short* bG = w2t + ((size_t)e * DDIM + nB) * FDIM + lq * 8;

    floatx4 acc[2][2];
#pragma unroll
    for (int i = 0; i < 2; ++i)
#pragma unroll
        for (int jn = 0; jn < 2; ++jn) acc[i][jn] = (floatx4)0.f;

    glds16(aG,      &As[0][w * 1024]);
    glds16(aG + 32, &As[0][w * 1024 + 512]);
    glds16(bG,      &Bs[0][w * 1024]);
    glds16(bG + 32, &Bs[0][w * 1024 + 512]);

    int p = 0;
    for (int k0 = 0; k0 < FDIM; k0 += 64) {
        __syncthreads();
        if (k0 + 64 < FDIM) {
            glds16(aG + k0 + 64, &As[p ^ 1][w * 1024]);
            glds16(aG + k0 + 96, &As[p ^ 1][w * 1024 + 512]);
            glds16(bG + k0 + 64, &Bs[p ^ 1][w * 1024]);
            glds16(bG + k0 + 96, &Bs[p ^ 1][w * 1024 + 512]);
        }
#pragma unroll
        for (int s = 0; s < 2; ++s) {
            short8 af[2], bf[2];
#pragma unroll
            for (int i = 0; i < 2; ++i)
                af[i] = *(const short8*)&As[p][((w & 1) * 2 + i) * 1024 + s * 512 + lane * 8];
#pragma unroll
            for (int jn = 0; jn < 2; ++jn)
                bf[jn] = *(const short8*)&Bs[p][((w >> 1) * 2 + jn) * 1024 + s * 512 + lane * 8];
#pragma unroll
            for (int i = 0; i < 2; ++i)
#pragma unroll
                for (int jn = 0; jn < 2; ++jn)
                    acc[i][jn] = __builtin_amdgcn_mfma_f32_16x16x32_bf16(af[i], bf[jn], acc[i][jn], 0, 0, 0);
        }
        p ^= 1;
    }
#pragma unroll
    for (int jn = 0; jn < 2; ++jn) {
        const int n = nt * 64 + wn + jn * 16 + lrow;
        const float bias = b2[e * DDIM + n];
#pragma unroll
        for (int i = 0; i < 2; ++i) {
#pragma unroll
            for (int r = 0; r < 4; ++r) {
                const int m = wm + i * 16 + lq * 4 + r;
                if (m < mloc) {
                    const int pp = list[m];
                    const int tok = pp >> 1;
                    const float v = (acc[i][jn][r] + bias) * wt[pp];
                    float* dst = (pp & 1) ? out1 : out0;
                    dst[(size_t)tok * DDIM + n] = v;
                }
            }
        }
    }
}

// ---------------- finalize: out = clip(x + out0 + out1) ----------------
__global__ __launch_bounds__(256) void finalize_kernel(
    const float* __restrict__ x, const float* __restrict__ o1,
    float* __restrict__ out)   // out currently holds out0
{
    const size_t i = ((size_t)blockIdx.x * 256 + threadIdx.x) * 4;
    float4 xv = *(const float4*)(x + i);
    float4 a  = *(const float4*)(out + i);
    float4 b  = *(const float4*)(o1 + i);
    float4 r;
    r.x = fminf(fmaxf(xv.x + a.x + b.x, -100.f), 100.f);
    r.y = fminf(fmaxf(xv.y + a.y + b.y, -100.f), 100.f);
    r.z = fminf(fmaxf(xv.z + a.z + b.z, -100.f), 100.f);
    r.w = fminf(fmaxf(xv.w + a.w + b.w, -100.f), 100.f);
    *(float4*)(out + i) = r;
}

extern "C" void kernel_launch(void* const* d_in, const int* in_sizes, int n_in,
                              void* d_out, int out_size, void* d_ws, size_t ws_size,
                              hipStream_t stream) {
    const float* h  = (const float*)d_in[0];
    const float* gw = (const float*)d_in[1];
    const float* w1 = (const float*)d_in[2];
    const float* b1 = (const float*)d_in[3];
    const float* w2 = (const float*)d_in[4];
    const float* b2 = (const float*)d_in[5];
    float* out = (float*)d_out;

    // workspace layout (bytes)
    char* ws = (char*)d_ws;
    int*   cnt    = (int*)ws;                          // 256
    int*   lists  = (int*)(ws + 256);                  // 114688
    float* wt     = (float*)(ws + 114944);             // 16384 -> 131328
    int*   job_e  = (int*)(ws + 131328);               // 512
    int*   job_mt = (int*)(ws + 131840);               // 512
    int*   njobs  = (int*)(ws + 132352);               // 256 -> 132608
    unsigned short* xb  = (unsigned short*)(ws + 262144);                 // 4 MB
    float* o1     = (float*)(ws + 262144 + 4194304);                      // 8 MB
    unsigned short* hhb = (unsigned short*)(ws + 262144 + 4194304 + 8388608);      // 16 MB
    unsigned short* wtb = (unsigned short*)(ws + 262144 + 4194304 + 8388608 + 16777216); // 58.72 MB (shared w1t then w2t)
    // total ~88.3 MB

    cvtx_kernel<<<NTOK * DDIM / (256 * 8), 256, 0, stream>>>(h, xb, cnt);
    gate_kernel<<<NTOK / 4, 256, 0, stream>>>(h, gw, cnt, lists, wt);
    jobs_kernel<<<1, 64, 0, stream>>>(cnt, job_e, job_mt, njobs);
    // w1 [1024][2048] -> w1t [2048][1024]; tiles/expert = (2048/64)*(1024/128) = 256
    cvtw_kernel<<<NEXP * 256, 256, 0, stream>>>(w1, wtb, DDIM, FDIM, DDIM / 128, 256);
    gemm1_kernel<<<dim3(FDIM / 128, MAXJOBS), 256, 0, stream>>>(xb, wtb, b1, cnt, lists, job_e, job_mt, njobs, hhb);
    // w2 [2048][1024] -> w2t [1024][2048]; tiles/expert = (1024/64)*(2048/128) = 256
    cvtw_kernel<<<NEXP * 256, 256, 0, stream>>>(w2, wtb, FDIM, DDIM, FDIM / 128, 256);
    gemm2_kernel<<<dim3(DDIM / 64, MAXJOBS), 256, 0, stream>>>(hhb, wtb, b2, cnt, lists, job_e, job_mt, njobs, wt, out, o1);
    finalize_kernel<<<NTOK * DDIM / (256 * 4), 256, 0, stream>>>(h, o1, out);
}